// Round 3
// baseline (202.808 us; speedup 1.0000x reference)
//
#include <hip/hip_runtime.h>
#include <hip/hip_bf16.h>

typedef __attribute__((ext_vector_type(8))) short  short8;
typedef __attribute__((ext_vector_type(4))) float  floatx4;

#define UH   2048    // U * H (row stride of inputs/hidden/out in floats)
#define XPAD 264     // 256 + 8 bf16 pad (528 B row stride, 16B aligned)

#define MFMA16(a,b,c) __builtin_amdgcn_mfma_f32_16x16x32_bf16(a, b, c, 0, 0, 0)

static __device__ __forceinline__ unsigned int pkbf16(float a, float b) {
    __hip_bfloat162 p = __float22bfloat162_rn(make_float2(a, b));
    return *(unsigned int*)&p;
}
static __device__ __forceinline__ float bf2f(unsigned short h) {
    unsigned int u = (unsigned int)h << 16;
    return *(float*)&u;
}

// ---------------- fused GRU kernel (single dispatch) --------------------------
// grid = 256 persistent (1 block/CU), 512 threads (8 waves), 8 m-tiles/block.
// Block bx: u = ((bx&7)<<1)|((bx>>3)&1) (XCD-paired: each XCD's 32 blocks touch
// only 2 u's -> W L2-resident); mt0 = (bx>>4)*8.
//
// SWAPPED MFMA operands: A = W-fragment (registers), B = X-fragment (LDS).
// Fragment layouts of A and B are the same lane pattern, so data movement is
// unchanged; D is transposed vs the old kernel: lane l, reg r ->
//   batch row m = (l&15) + 16*m4,  gate col c = (l>>4)*4 + r + 16*wv
// => epilogue writes 4 coalesced float4 stores/thread, hv via ds_read_b64,
//    bias folds into accumulator INIT (MFMA accumulates on top).
//
// W-fragments are PINNED with opaque identity asm after the one-time load:
// round-1 counters (VGPR_Count=112 vs ~210 live) proved the allocator
// rematerialized the fragment loads into the tile loop (L2 reload every tile).
// The asm makes the loaded value non-rematerializable; bounds (512,2) caps at
// 256 VGPR so ~230 allocs without spill.
__global__ __launch_bounds__(512, 2) void gru_fused(
    const float* __restrict__ inputs, const float* __restrict__ hidden,
    const float* __restrict__ w_ih,   const float* __restrict__ w_hh,
    const float* __restrict__ b_ih,   const float* __restrict__ b_hh,
    float* __restrict__ out)
{
    __shared__ __align__(16) __hip_bfloat16 Xs[2][64][XPAD];

    const int bx   = blockIdx.x;
    const int u    = ((bx & 7) << 1) | ((bx >> 3) & 1);  // XCD-local u pair
    const int mt0  = (bx >> 4) * 8;                      // first of 8 m-tiles
    const int tid  = threadIdx.x;
    const int lane = tid & 63;
    const int wv   = tid >> 6;     // [0,8): wave owns output cols [16*wv,16*wv+16)
    const int lr   = lane & 15;
    const int lq   = lane >> 4;

    // ---- W fragments: direct fp32 load + pack, once per block ---------------
    // A-fragment (gt,s): lane elem j = W[u][gt*16+lr][s*32+lq*8+j]
    auto loadW = [&](int gt, int s) -> short8 {
        const int row = gt * 16 + lr;
        const int k0  = s * 32 + lq * 8;          // k<128 -> w_ih, else w_hh
        const float* src = (k0 < 128)
            ? (w_ih + (size_t)(u * 384 + row) * 128 + k0)
            : (w_hh + (size_t)(u * 384 + row) * 128 + (k0 - 128));
        float4 v0 = ((const float4*)src)[0];
        float4 v1 = ((const float4*)src)[1];
        union { uint4 q; short8 s8; } cvt;
        cvt.q.x = pkbf16(v0.x, v0.y);
        cvt.q.y = pkbf16(v0.z, v0.w);
        cvt.q.z = pkbf16(v1.x, v1.y);
        cvt.q.w = pkbf16(v1.z, v1.w);
        return cvt.s8;
    };
    short8 fR[8], fZ[8], fN[8];
    #pragma unroll
    for (int s = 0; s < 8; ++s) {
        fR[s] = loadW(     wv, s);
        fZ[s] = loadW( 8 + wv, s);
        fN[s] = loadW(16 + wv, s);
    }

    // ---- bias (thread covers cols c0..c0+3), folded into acc init -----------
    const int c0 = wv * 16 + lq * 4;
    float4 bi = *(const float4*)(b_ih + u * 384 +       c0);
    float4 bh = *(const float4*)(b_hh + u * 384 +       c0);
    float4 zi = *(const float4*)(b_ih + u * 384 + 128 + c0);
    float4 zh = *(const float4*)(b_hh + u * 384 + 128 + c0);
    float4 ni = *(const float4*)(b_ih + u * 384 + 256 + c0);
    float4 nh = *(const float4*)(b_hh + u * 384 + 256 + c0);
    const floatx4 accR0  = (floatx4){bi.x + bh.x, bi.y + bh.y, bi.z + bh.z, bi.w + bh.w};
    const floatx4 accZ0  = (floatx4){zi.x + zh.x, zi.y + zh.y, zi.z + zh.z, zi.w + zh.w};
    const floatx4 accXN0 = (floatx4){ni.x, ni.y, ni.z, ni.w};
    const floatx4 accHN0 = (floatx4){nh.x, nh.y, nh.z, nh.w};

    // ---- staging geometry: thread loads 16B at col scol, rows wv + 8*i ------
    const int scol = (tid & 63) * 4;                   // float col in [0,256)
    const float* sbase = ((scol < 128) ? (inputs + scol)
                                       : (hidden + (scol - 128)))
                       + (size_t)u * 128;

    float4 stg[8];   // in-flight tile (32 VGPR)

    auto ISSUE = [&](int mt) {
        const float* p = sbase + (size_t)(mt * 64 + wv) * UH;
        #pragma unroll
        for (int i = 0; i < 8; ++i)
            stg[i] = *(const float4*)(p + (size_t)(i * 8) * UH);
    };
    auto WRITE = [&](int buf) {
        #pragma unroll
        for (int i = 0; i < 8; ++i) {
            uint2 w;
            w.x = pkbf16(stg[i].x, stg[i].y);
            w.y = pkbf16(stg[i].z, stg[i].w);
            *(uint2*)&Xs[buf][i * 8 + wv][scol] = w;
        }
    };
    auto BARRIER = [&]() {
        // drain LDS only; global prefetch loads stay in flight across barrier
        asm volatile("s_waitcnt lgkmcnt(0)" ::: "memory");
        __builtin_amdgcn_sched_barrier(0);
        __builtin_amdgcn_s_barrier();
        __builtin_amdgcn_sched_barrier(0);
    };

    // ---- prologue -----------------------------------------------------------
    ISSUE(mt0 + 0);                 // overlap X loads with W-load latency
    // PIN: values become asm-defined -> loads cannot be sunk/rematerialized.
    #pragma unroll
    for (int s = 0; s < 8; ++s) {
        asm volatile("" : "+v"(fR[s]));
        asm volatile("" : "+v"(fZ[s]));
        asm volatile("" : "+v"(fN[s]));
    }
    WRITE(0);
    ISSUE(mt0 + 1);
    BARRIER();

    #pragma unroll 1
    for (int j = 0; j < 8; ++j) {
        const int buf = j & 1;

        // ---- compute tile j from Xs[buf]: D rows=c, cols=m ------------------
        floatx4 aR[4], aZ[4], aXN[4], aHN[4];
        #pragma unroll
        for (int m4 = 0; m4 < 4; ++m4) {
            aR[m4]  = accR0;
            aZ[m4]  = accZ0;
            aXN[m4] = accXN0;
            aHN[m4] = accHN0;
        }
        #pragma unroll
        for (int s = 0; s < 8; ++s) {
            short8 xF[4];
            #pragma unroll
            for (int m4 = 0; m4 < 4; ++m4)
                xF[m4] = *(const short8*)((const short*)&Xs[buf][m4 * 16 + lr][0]
                                          + s * 32 + lq * 8);
            #pragma unroll
            for (int m4 = 0; m4 < 4; ++m4) {
                aR[m4] = MFMA16(fR[s], xF[m4], aR[m4]);
                aZ[m4] = MFMA16(fZ[s], xF[m4], aZ[m4]);
                if (s < 4) aXN[m4] = MFMA16(fN[s], xF[m4], aXN[m4]);
                else       aHN[m4] = MFMA16(fN[s], xF[m4], aHN[m4]);
            }
        }

        // ---- pipeline: land tile j+1, launch tile j+2 BEFORE epilogue -------
        if (j < 7) {
            WRITE(buf ^ 1);                  // waits only its own stg vmcnt
            if (j < 6) ISSUE(mt0 + j + 2);   // streams under the epilogue
        }

        // ---- epilogue: thread owns (m = m4*16+lr, cols c0..c0+3) ------------
        #pragma unroll
        for (int m4 = 0; m4 < 4; ++m4) {
            const int m = m4 * 16 + lr;
            ushort4 hq = *(const ushort4*)&Xs[buf][m][128 + c0];
            unsigned short hs[4] = {hq.x, hq.y, hq.z, hq.w};
            float4 o;
            float* op = (float*)&o;
            #pragma unroll
            for (int r = 0; r < 4; ++r) {
                float rv = __builtin_amdgcn_rcpf(1.f + __expf(-aR[m4][r]));
                float zv = __builtin_amdgcn_rcpf(1.f + __expf(-aZ[m4][r]));
                float npre = aXN[m4][r] + rv * aHN[m4][r];
                float nv = 2.f * __builtin_amdgcn_rcpf(1.f + __expf(-2.f * npre)) - 1.f;
                float hv = bf2f(hs[r]);      // original hidden (bf16)
                op[r] = nv + zv * (hv - nv);
            }
            float* orow = out + (size_t)((mt0 + j) * 64 + m) * UH + u * 128 + c0;
            *(float4*)orow = o;
        }

        if (j < 7) BARRIER();
    }
}

// ---------------- launch ------------------------------------------------------

extern "C" void kernel_launch(void* const* d_in, const int* in_sizes, int n_in,
                              void* d_out, int out_size, void* d_ws, size_t ws_size,
                              hipStream_t stream) {
    const float* inputs = (const float*)d_in[0];
    const float* hidden = (const float*)d_in[1];
    const float* w_ih   = (const float*)d_in[2];
    const float* w_hh   = (const float*)d_in[3];
    const float* b_ih   = (const float*)d_in[4];
    const float* b_hh   = (const float*)d_in[5];
    float* out = (float*)d_out;

    gru_fused<<<dim3(256), dim3(512), 0, stream>>>(inputs, hidden,
                                                   w_ih, w_hh, b_ih, b_hh, out);
}